// Round 11
// baseline (161.950 us; speedup 1.0000x reference)
//
#include <hip/hip_runtime.h>
#include <hip/hip_fp16.h>

#define HH 512
#define WW 512
#define HW (HH*WW)
#define EPV 1e-20f

// R20: wall ~= steps/wave x per-step stall (R12-R19 law; TLP only needs
// residency). Two step-cutters:
// (1) prep: depth-13 fp16 raw ring, ONE load-pair/step (ring serves add r,
//     center r-4, subtract r-8; 3-ahead prefetch; slots (t+k)%13 are
//     compile-time in the unrolled loop). Exact telescoping (add/sub use
//     identical fp16-rounded values). VGPR ~155 @ waves_per_eu(3,3).
// (2) ncc: warm-up fusion -- 2 product rows/step for the first 4 steps
//     (8 adds by t=3, first emit t=3), 7 steady steps: 15 -> 11 steps.
//     Sub fifo 1-slack (R18-proven). Residency 6/CU <= 8/CU @ (2,2).
// Keeps: 8-col centered windows, fp16 intermediates, XCD-chunked ncc,
// per-z wsum + fin, barrier-free.

__device__ __forceinline__ float bpl(int addr, float v) {
    return __int_as_float(__builtin_amdgcn_ds_bpermute(addr, __float_as_int(v)));
}
__device__ __forceinline__ int rcl(int r) { return min(max(r, 0), HH - 1); }

__device__ __forceinline__ float4 h2f4(uint2 r) {
    __half2 lo = *(__half2*)&r.x, hi = *(__half2*)&r.y;
    float2 a = __half22float2(lo), b = __half22float2(hi);
    return make_float4(a.x, a.y, b.x, b.y);
}
__device__ __forceinline__ uint2 f2h4(float4 v) {
    __half2 lo = __floats2half2_rn(v.x, v.y);
    __half2 hi = __floats2half2_rn(v.z, v.w);
    uint2 r;
    r.x = *(unsigned int*)&lo;
    r.y = *(unsigned int*)&hi;
    return r;
}
__device__ __forceinline__ uint4 pack8(float4 a, float4 b) {
    uint2 lo = f2h4(a), hi = f2h4(b);
    return make_uint4(lo.x, lo.y, hi.x, hi.y);
}
__device__ __forceinline__ void unpack8(uint4 r, float4& a, float4& b) {
    a = h2f4(make_uint2(r.x, r.y));
    b = h2f4(make_uint2(r.z, r.w));
}

// ---------------- prep: raw -> fp16 centered (ac) + fp16 1/sqrt(var box) --
// One wave per (z, 8-row seg), full 512-col rows. 23 steps.
// r = y0-7+t (VA add), c = r-4 (ac), y = c-4 (rs).
// Ring rg[13] of packed-fp16 raw rows; slotOf(row offset d=row-y0) =
// (d+13)%13; add slot (t+6)%13, sub (t+11)%13, center (t+2)%13,
// prefetch row y0-4+t -> slot (t+9)%13 (3-ahead).
__global__ void __launch_bounds__(64)
__attribute__((amdgpu_waves_per_eu(3, 3)))
prep_f8(const float* __restrict__ outs, const float* __restrict__ labs,
        __half* __restrict__ ac, __half* __restrict__ rs,
        float* __restrict__ wsum)
{
    const int l = threadIdx.x;
    if (blockIdx.x == 0 && blockIdx.y == 0 && l < 24)
        wsum[l * 64] = 0.f;                   // zero per-z partial slots
    const int y0 = 8 * blockIdx.x;
    const int z  = blockIdx.y;

    const float* src = (z < 24) ? outs + z * HW : labs + (z - 24) * HW;
    __half* acd = ac + z * HW;
    __half* rsd = rs + z * HW;

    const int   col = 8 * l;
    const int   aL1 = ((l - 1) & 63) << 2;
    const int   aR1 = ((l + 1) & 63) << 2;
    const float lmE = (l > 0)  ? 1.f : 0.f;
    const float rmE = (l < 63) ? 1.f : 0.f;

    auto ldpack = [&](int row) {
        float4 a = *(const float4*)&src[row * WW + col];
        float4 b = *(const float4*)&src[row * WW + col + 4];
        return pack8(a, b);
    };

    uint4 rg[13];
    uint4 pk[8];             // packed-fp16 ac ring (variance subtract)
    float4 VAa = {0,0,0,0}, VAb = {0,0,0,0};
    float4 Vqa = {0,0,0,0}, Vqb = {0,0,0,0};
    #pragma unroll
    for (int k = 0; k < 13; ++k) rg[k] = make_uint4(0,0,0,0);
    #pragma unroll
    for (int k = 0; k < 8; ++k) pk[k] = make_uint4(0,0,0,0);
    // preload rows y0-7..y0-5 (offsets -7,-6,-5 -> slots 6,7,8)
    rg[6] = ldpack(rcl(y0 - 7));
    rg[7] = ldpack(rcl(y0 - 6));
    rg[8] = ldpack(rcl(y0 - 5));

    auto step = [&](const int t) {
        const int   r  = y0 - 7 + t;
        const float rm = (r >= 0 && r < HH) ? 1.f : 0.f;
        {   // VA += raw(r), ring slot (t+6)%13 (loaded at t-3 / preloaded)
            float4 ra, rb; unpack8(rg[(t + 6) % 13], ra, rb);
            VAa.x += ra.x*rm; VAa.y += ra.y*rm; VAa.z += ra.z*rm; VAa.w += ra.w*rm;
            VAb.x += rb.x*rm; VAb.y += rb.y*rm; VAb.z += rb.z*rm; VAb.w += rb.w*rm;
        }
        if (t >= 8) {   // VA -= raw(r-8), slot (t+11)%13 (identical values)
            const float rm8 = ((r - 8) >= 0) ? 1.f : 0.f;
            float4 oa, ob; unpack8(rg[(t + 11) % 13], oa, ob);
            VAa.x -= oa.x*rm8; VAa.y -= oa.y*rm8; VAa.z -= oa.z*rm8; VAa.w -= oa.w*rm8;
            VAb.x -= ob.x*rm8; VAb.y -= ob.y*rm8; VAb.z -= ob.z*rm8; VAb.w -= ob.w*rm8;
        }
        if (t <= 19) {  // prefetch row y0-4+t into slot (t+9)%13 (3-ahead)
            rg[(t + 9) % 13] = ldpack(rcl(y0 - 4 + t));
        }
        if (t >= 8) {
            const int   c  = r - 4;
            const float cm = (c >= 0 && c < HH) ? 1.f : 0.f;
            // centered 8-wide window on VA (mean box, 64 px)
            float p1 = VAa.x, p2 = p1+VAa.y, p3 = p2+VAa.z, p4 = p3+VAa.w;
            float p5 = p4+VAb.x, p6 = p5+VAb.y, p7 = p6+VAb.z, tt = p7+VAb.w;
            float s1 = VAb.w, s2 = VAb.z+s1, s3 = VAb.y+s2;
            float L1 = bpl(aL1, s1)*lmE, L2 = bpl(aL1, s2)*lmE, L3 = bpl(aL1, s3)*lmE;
            float R1 = bpl(aR1, p1)*rmE, R2 = bpl(aR1, p2)*rmE;
            float R3 = bpl(aR1, p3)*rmE, R4 = bpl(aR1, p4)*rmE;
            // raw row c from ring slot (t+2)%13 (loaded at t-7)
            float4 rc0, rc1; unpack8(rg[(t + 2) % 13], rc0, rc1);
            float4 aL4, aH4;
            aL4.x = (rc0.x - (L3+p5)    * (1.f/64.f)) * cm;
            aL4.y = (rc0.y - (L2+p6)    * (1.f/64.f)) * cm;
            aL4.z = (rc0.z - (L1+p7)    * (1.f/64.f)) * cm;
            aL4.w = (rc0.w - tt         * (1.f/64.f)) * cm;
            aH4.x = (rc1.x - (tt-p1+R1) * (1.f/64.f)) * cm;
            aH4.y = (rc1.y - (tt-p2+R2) * (1.f/64.f)) * cm;
            aH4.z = (rc1.z - (tt-p3+R3) * (1.f/64.f)) * cm;
            aH4.w = (rc1.w - (tt-p4+R4) * (1.f/64.f)) * cm;
            uint4 pkNew = pack8(aL4, aH4);
            if (t >= 11 && t <= 18)           // store own 8 rows
                *(uint4*)&acd[c * WW + col] = pkNew;
            // variance slide on the ROUNDED values (exact telescoping)
            float4 qnL, qnH; unpack8(pkNew, qnL, qnH);
            Vqa.x += qnL.x*qnL.x; Vqa.y += qnL.y*qnL.y;
            Vqa.z += qnL.z*qnL.z; Vqa.w += qnL.w*qnL.w;
            Vqb.x += qnH.x*qnH.x; Vqb.y += qnH.y*qnH.y;
            Vqb.z += qnH.z*qnH.z; Vqb.w += qnH.w*qnH.w;
            if (t >= 16) {                    // subtract sq(ac(c-8))
                float4 oL, oH; unpack8(pk[t & 7], oL, oH);
                Vqa.x -= oL.x*oL.x; Vqa.y -= oL.y*oL.y;
                Vqa.z -= oL.z*oL.z; Vqa.w -= oL.w*oL.w;
                Vqb.x -= oH.x*oH.x; Vqb.y -= oH.y*oH.y;
                Vqb.z -= oH.z*oH.z; Vqb.w -= oH.w*oH.w;
            }
            pk[t & 7] = pkNew;
            if (t >= 15 && t <= 22) {         // emit rs at row y = c-4
                const int y = c - 4;          // y in [y0, y0+7]
                float q1 = Vqa.x, q2 = q1+Vqa.y, q3 = q2+Vqa.z, q4 = q3+Vqa.w;
                float q5 = q4+Vqb.x, q6 = q5+Vqb.y, q7 = q6+Vqb.z, qt = q7+Vqb.w;
                float z1 = Vqb.w, z2 = Vqb.z+z1, z3 = Vqb.y+z2;
                float Lq1 = bpl(aL1, z1)*lmE, Lq2 = bpl(aL1, z2)*lmE, Lq3 = bpl(aL1, z3)*lmE;
                float Rq1 = bpl(aR1, q1)*rmE, Rq2 = bpl(aR1, q2)*rmE;
                float Rq3 = bpl(aR1, q3)*rmE, Rq4 = bpl(aR1, q4)*rmE;
                float4 rL, rH;
                rL.x = fminf(__frsqrt_rn(fmaxf(Lq3+q5,    EPV)), 60000.f);
                rL.y = fminf(__frsqrt_rn(fmaxf(Lq2+q6,    EPV)), 60000.f);
                rL.z = fminf(__frsqrt_rn(fmaxf(Lq1+q7,    EPV)), 60000.f);
                rL.w = fminf(__frsqrt_rn(fmaxf(qt,        EPV)), 60000.f);
                rH.x = fminf(__frsqrt_rn(fmaxf(qt-q1+Rq1, EPV)), 60000.f);
                rH.y = fminf(__frsqrt_rn(fmaxf(qt-q2+Rq2, EPV)), 60000.f);
                rH.z = fminf(__frsqrt_rn(fmaxf(qt-q3+Rq3, EPV)), 60000.f);
                rH.w = fminf(__frsqrt_rn(fmaxf(qt-q4+Rq4, EPV)), 60000.f);
                *(uint4*)&rsd[y * WW + col] = pack8(rL, rH);
            }
        }
    };
    #pragma unroll
    for (int t = 0; t < 23; ++t) step(t);
}

// ---------------- main: product boxes, warm-up-fused 11-step pipeline -----
// One wave per (z, 8-row seg). Steps 0..3: add TWO product rows each
// (y0-3..y0+4), emit y0 at t=3. Steps 4..10: add y0+t+1, subtract y0+t-7,
// emit y0+t-3. 1536 waves, XCD-chunked.
__global__ void __launch_bounds__(64)
__attribute__((amdgpu_waves_per_eu(2, 2)))
ncc_f8(const __half* __restrict__ ac, const __half* __restrict__ rs,
       float* __restrict__ wsum)
{
    const int l   = threadIdx.x;
    const int n   = blockIdx.x;            // 0..1535
    const int xcd = n & 7;
    const int p   = n >> 3;                // 0..191
    const int zq  = p >> 6;                // 0..2
    const int seg = p & 63;                // 0..63
    const int z   = 3 * xcd + zq;          // b*6 + i
    const int b   = z / 6;
    const int y0  = 8 * seg;

    const __half* acp = ac + z * HW;
    const __half* sip = rs + z * HW;
    const __half* bcp[4]; const __half* sjp[4];
    #pragma unroll
    for (int j = 0; j < 4; ++j) {
        bcp[j] = ac + (24 + b * 4 + j) * HW;
        sjp[j] = rs + (24 + b * 4 + j) * HW;
    }

    const int   col = 8 * l;
    const int   aL1 = ((l - 1) & 63) << 2;
    const int   aR1 = ((l + 1) & 63) << 2;
    const float lmE = (l > 0)  ? 1.f : 0.f;
    const float rmE = (l < 63) ? 1.f : 0.f;

    auto lda = [&](const __half* ptr, int row) {
        return *(const uint4*)&ptr[row * WW + col];
    };

    uint4 fa[2], fb[4][2];                 // row buffers (warm: pair; steady: ping)
    uint4 oA, oB[4];                       // subtract row (1-slack)
    uint4 psiB[2], psjB[2][4];
    float4 VpL[4], VpH[4];
    float4 xsL = make_float4(0,0,0,0), xsH = make_float4(0,0,0,0);
    {
        const int r0 = rcl(y0 - 3), r1 = rcl(y0 - 2);
        fa[0] = lda(acp, r0); fa[1] = lda(acp, r1);
        #pragma unroll
        for (int j = 0; j < 4; ++j) {
            fb[j][0] = lda(bcp[j], r0); fb[j][1] = lda(bcp[j], r1);
            oB[j] = make_uint4(0,0,0,0);
            psjB[0][j] = make_uint4(0,0,0,0); psjB[1][j] = make_uint4(0,0,0,0);
            VpL[j] = make_float4(0,0,0,0); VpH[j] = make_float4(0,0,0,0);
        }
        oA = make_uint4(0,0,0,0);
        psiB[0] = make_uint4(0,0,0,0); psiB[1] = make_uint4(0,0,0,0);
    }

    // Vp accumulate row (m = +rm for add, -rm for subtract)
    auto accRow = [&](uint4 a, uint4 b0, uint4 b1, uint4 b2, uint4 b3, float m) {
        float4 avL, avH; unpack8(a, avL, avH);
        avL.x *= m; avL.y *= m; avL.z *= m; avL.w *= m;
        avH.x *= m; avH.y *= m; avH.z *= m; avH.w *= m;
        float4 bL, bH;
        unpack8(b0, bL, bH);
        VpL[0].x += avL.x*bL.x; VpL[0].y += avL.y*bL.y; VpL[0].z += avL.z*bL.z; VpL[0].w += avL.w*bL.w;
        VpH[0].x += avH.x*bH.x; VpH[0].y += avH.y*bH.y; VpH[0].z += avH.z*bH.z; VpH[0].w += avH.w*bH.w;
        unpack8(b1, bL, bH);
        VpL[1].x += avL.x*bL.x; VpL[1].y += avL.y*bL.y; VpL[1].z += avL.z*bL.z; VpL[1].w += avL.w*bL.w;
        VpH[1].x += avH.x*bH.x; VpH[1].y += avH.y*bH.y; VpH[1].z += avH.z*bH.z; VpH[1].w += avH.w*bH.w;
        unpack8(b2, bL, bH);
        VpL[2].x += avL.x*bL.x; VpL[2].y += avL.y*bL.y; VpL[2].z += avL.z*bL.z; VpL[2].w += avL.w*bL.w;
        VpH[2].x += avH.x*bH.x; VpH[2].y += avH.y*bH.y; VpH[2].z += avH.z*bH.z; VpH[2].w += avH.w*bH.w;
        unpack8(b3, bL, bH);
        VpL[3].x += avL.x*bL.x; VpL[3].y += avL.y*bL.y; VpL[3].z += avL.z*bL.z; VpL[3].w += avL.w*bL.w;
        VpH[3].x += avH.x*bH.x; VpH[3].y += avH.y*bH.y; VpH[3].z += avH.z*bH.z; VpH[3].w += avH.w*bH.w;
    };
    auto emitRow = [&](uint4 cPsi, const uint4* cPsj) {
        float4 pL, pH; unpack8(cPsi, pL, pH);
        float4 mmL = make_float4(-1,-1,-1,-1), mmH = make_float4(-1,-1,-1,-1);
        #pragma unroll
        for (int j = 0; j < 4; ++j) {
            float q1 = VpL[j].x, q2 = q1+VpL[j].y, q3 = q2+VpL[j].z, q4 = q3+VpL[j].w;
            float q5 = q4+VpH[j].x, q6 = q5+VpH[j].y, q7 = q6+VpH[j].z, q8 = q7+VpH[j].w;
            float s1 = VpH[j].w, s2 = VpH[j].z+s1, s3 = VpH[j].y+s2;
            float L1 = bpl(aL1, s1)*lmE, L2 = bpl(aL1, s2)*lmE, L3 = bpl(aL1, s3)*lmE;
            float R1 = bpl(aR1, q1)*rmE, R2 = bpl(aR1, q2)*rmE;
            float R3 = bpl(aR1, q3)*rmE, R4 = bpl(aR1, q4)*rmE;
            float4 sL, sH; unpack8(cPsj[j], sL, sH);
            mmL.x = fmaxf(mmL.x, (L3+q5)    * (pL.x*sL.x));
            mmL.y = fmaxf(mmL.y, (L2+q6)    * (pL.y*sL.y));
            mmL.z = fmaxf(mmL.z, (L1+q7)    * (pL.z*sL.z));
            mmL.w = fmaxf(mmL.w, q8         * (pL.w*sL.w));
            mmH.x = fmaxf(mmH.x, (q8-q1+R1) * (pH.x*sH.x));
            mmH.y = fmaxf(mmH.y, (q8-q2+R2) * (pH.y*sH.y));
            mmH.z = fmaxf(mmH.z, (q8-q3+R3) * (pH.z*sH.z));
            mmH.w = fmaxf(mmH.w, (q8-q4+R4) * (pH.w*sH.w));
        }
        xsL.x += 1.f - fminf(mmL.x, 1.f);
        xsL.y += 1.f - fminf(mmL.y, 1.f);
        xsL.z += 1.f - fminf(mmL.z, 1.f);
        xsL.w += 1.f - fminf(mmL.w, 1.f);
        xsH.x += 1.f - fminf(mmH.x, 1.f);
        xsH.y += 1.f - fminf(mmH.y, 1.f);
        xsH.z += 1.f - fminf(mmH.z, 1.f);
        xsH.w += 1.f - fminf(mmH.w, 1.f);
    };

    #pragma unroll
    for (int t = 0; t < 11; ++t) {
        // capture psi for this step's emit (loaded 2 steps ago, slot t&1)
        uint4 cPsi = psiB[t & 1];
        uint4 cPsj[4] = { psjB[t & 1][0], psjB[t & 1][1],
                          psjB[t & 1][2], psjB[t & 1][3] };
        if (t <= 3) {
            // ---- warm-up: add rows w0 = y0-3+2t (slot 0), w0+1 (slot 1)
            const int w0 = y0 - 3 + 2 * t;
            uint4 a0 = fa[0], a1 = fa[1];
            uint4 b00 = fb[0][0], b10 = fb[1][0], b20 = fb[2][0], b30 = fb[3][0];
            uint4 b01 = fb[0][1], b11 = fb[1][1], b21 = fb[2][1], b31 = fb[3][1];
            if (t <= 2) {        // next warm pair (1-slack)
                const int n0 = rcl(w0 + 2), n1 = rcl(w0 + 3);
                fa[0] = lda(acp, n0); fa[1] = lda(acp, n1);
                #pragma unroll
                for (int j = 0; j < 4; ++j) {
                    fb[j][0] = lda(bcp[j], n0); fb[j][1] = lda(bcp[j], n1);
                }
            } else {             // t==3: stage steady rows y0+5 (t=4), y0+6 (t=5)
                const int n0 = rcl(y0 + 5), n1 = rcl(y0 + 6);
                fa[0] = lda(acp, n0); fa[1] = lda(acp, n1);
                #pragma unroll
                for (int j = 0; j < 4; ++j) {
                    fb[j][0] = lda(bcp[j], n0); fb[j][1] = lda(bcp[j], n1);
                }
                const int ro = rcl(y0 - 3);          // sub row for t=4
                oA = lda(acp, ro);
                #pragma unroll
                for (int j = 0; j < 4; ++j) oB[j] = lda(bcp[j], ro);
            }
            const float m0 = (w0     >= 0) ? 1.f : 0.f;
            const float m1 = (w0 + 1 >= 0) ? 1.f : 0.f;
            accRow(a0, b00, b10, b20, b30, m0);
            accRow(a1, b01, b11, b21, b31, m1);
            if (t >= 1) {        // psi for emit at t+2: row y0+t-1
                const int yn = y0 + t - 1;
                psiB[t & 1] = lda(sip, yn);
                #pragma unroll
                for (int j = 0; j < 4; ++j) psjB[t & 1][j] = lda(sjp[j], yn);
            }
            if (t == 3) emitRow(cPsi, cPsj);         // row y0 (psi loaded t=1)
        } else {
            // ---- steady: add y0+t+1, subtract y0+t-7, emit y0+t-3
            const int cadd = y0 + t + 1;
            uint4 ar = fa[t & 1];
            uint4 br0 = fb[0][t & 1], br1 = fb[1][t & 1];
            uint4 br2 = fb[2][t & 1], br3 = fb[3][t & 1];
            uint4 arO = oA;
            uint4 bo0 = oB[0], bo1 = oB[1], bo2 = oB[2], bo3 = oB[3];
            if (t <= 8) {        // add row for t+2
                const int rn = rcl(cadd + 2);
                fa[t & 1] = lda(acp, rn);
                #pragma unroll
                for (int j = 0; j < 4; ++j) fb[j][t & 1] = lda(bcp[j], rn);
            }
            if (t <= 9) {        // sub row for t+1: y0+t-6
                const int ro = rcl(y0 + t - 6);
                oA = lda(acp, ro);
                #pragma unroll
                for (int j = 0; j < 4; ++j) oB[j] = lda(bcp[j], ro);
            }
            if (t <= 8) {        // psi for emit at t+2: row y0+t-1
                const int yn = y0 + t - 1;
                psiB[t & 1] = lda(sip, yn);
                #pragma unroll
                for (int j = 0; j < 4; ++j) psjB[t & 1][j] = lda(sjp[j], yn);
            }
            const float mA = (cadd < HH) ? 1.f : 0.f;
            accRow(ar, br0, br1, br2, br3, mA);
            const float mO = ((y0 + t - 7) >= 0) ? -1.f : 0.f;
            accRow(arO, bo0, bo1, bo2, bo3, mO);
            emitRow(cPsi, cPsj);                     // row y0+t-3
        }
    }

    float xt = xsL.x + xsL.y + xsL.z + xsL.w + xsH.x + xsH.y + xsH.z + xsH.w;
    #pragma unroll
    for (int off = 32; off > 0; off >>= 1) xt += __shfl_down(xt, off);
    if (l == 0) atomicAdd(&wsum[z * 64], xt);
}

// ---------------- finalize: 24 partials -> 25 outputs ---------------------
__global__ void fin_f4(const float* __restrict__ wsum, float* __restrict__ out)
{
    const int l = threadIdx.x;
    float v = (l < 24) ? wsum[l * 64] : 0.f;
    if (l < 24) out[1 + l] = v * (1.f / (float)HW);
    #pragma unroll
    for (int off = 32; off > 0; off >>= 1) v += __shfl_down(v, off);
    if (l == 0) out[0] = v * (1.f / (24.f * (float)HW));
}

extern "C" void kernel_launch(void* const* d_in, const int* in_sizes, int n_in,
                              void* d_out, int out_size, void* d_ws, size_t ws_size,
                              hipStream_t stream) {
    const float* outs = (const float*)d_in[0];   // (4,6,512,512)
    const float* labs = (const float*)d_in[1];   // (4,4,512,512)
    float* out = (float*)d_out;                  // 25 floats
    float* ws  = (float*)d_ws;

    __half* acw  = (__half*)ws;            // 40*HW halves (a:0..23, b:24..39)
    __half* rsw  = (__half*)ws + 40 * HW;  // 40*HW halves (fp16 1/sqrt(var))
    float*  wsum = ws + 40 * HW;           // floats: after the two half arrays

    // prep: 64 segs(8 rows) x 40 images, full-width waves (also zeroes wsum)
    prep_f8<<<dim3(64, 40), 64, 0, stream>>>(outs, labs, acw, rsw, wsum);
    // main: 1536 blocks (24 z x 64 segs of 8 rows), XCD-chunked decode
    ncc_f8<<<dim3(1536, 1, 1), 64, 0, stream>>>(acw, rsw, wsum);
    // finalize: one wave
    fin_f4<<<dim3(1, 1, 1), 64, 0, stream>>>(wsum, out);
}

// Round 12
// 139.900 us; speedup vs baseline: 1.1576x; 1.1576x over previous
//
#include <hip/hip_runtime.h>
#include <hip/hip_fp16.h>

#define HH 512
#define WW 512
#define HW (HH*WW)
#define EPV 1e-20f

// R21 = R19 (proven 129.8us, absmax 0.0) + prep XCD-chunking.
// R20 post-mortem: both step-fusion changes spilled (ncc WRITE 50MB scratch,
// one 20ms dispatch; prep WRITE +28MB) -- on this compiler, raising peak
// live state converts to scratch, costing far more than the steps saved.
// Reverted wholesale. New lever: prep FETCH was 92.5MB vs ~48MB ideal --
// default round-robin scatters each image's 64 seg-waves across all 8 XCDs
// (every L2 fetches every image). XCD-chunk: XCD k owns images 5k..5k+4,
// so each image is fetched by exactly one L2 (T1, proven on ncc in R12).
// Keeps: 8-col centered windows, fp16 intermediates, raw ring (1 load-pair
// +1 fifo pair/step), exact telescoping, waves_per_eu pins, XCD-chunked ncc,
// per-z wsum + fin, barrier-free.

__device__ __forceinline__ float bpl(int addr, float v) {
    return __int_as_float(__builtin_amdgcn_ds_bpermute(addr, __float_as_int(v)));
}
__device__ __forceinline__ int rcl(int r) { return min(max(r, 0), HH - 1); }

__device__ __forceinline__ float4 h2f4(uint2 r) {
    __half2 lo = *(__half2*)&r.x, hi = *(__half2*)&r.y;
    float2 a = __half22float2(lo), b = __half22float2(hi);
    return make_float4(a.x, a.y, b.x, b.y);
}
__device__ __forceinline__ uint2 f2h4(float4 v) {
    __half2 lo = __floats2half2_rn(v.x, v.y);
    __half2 hi = __floats2half2_rn(v.z, v.w);
    uint2 r;
    r.x = *(unsigned int*)&lo;
    r.y = *(unsigned int*)&hi;
    return r;
}
__device__ __forceinline__ uint4 pack8(float4 a, float4 b) {
    uint2 lo = f2h4(a), hi = f2h4(b);
    return make_uint4(lo.x, lo.y, hi.x, hi.y);
}
__device__ __forceinline__ void unpack8(uint4 r, float4& a, float4& b) {
    a = h2f4(make_uint2(r.x, r.y));
    b = h2f4(make_uint2(r.z, r.w));
}

// ---------------- prep: raw -> fp16 centered (ac) + fp16 1/sqrt(var box) --
// One wave per (z, 8-row seg), full 512-col rows. 23 steps. XCD-chunked:
// XCD k owns z in {5k..5k+4} (each image hits exactly one L2).
// r = y0-7+t (VA add row), c = r-4 (ac row), y = c-4 (rs row).
// Raw ring rg[8]: slot t&7 = row r (written at t-2); center = slot (t+4)&7.
__global__ void __launch_bounds__(64)
__attribute__((amdgpu_waves_per_eu(3, 3)))
prep_f8(const float* __restrict__ outs, const float* __restrict__ labs,
        __half* __restrict__ ac, __half* __restrict__ rs,
        float* __restrict__ wsum)
{
    const int l = threadIdx.x;
    const int n = blockIdx.x;              // 0..2559
    if (n == 0 && l < 24)
        wsum[l * 64] = 0.f;                // zero per-z partial slots
    const int xcd = n & 7;                 // block n -> XCD n%8 (round-robin)
    const int p   = n >> 3;                // 0..319 within XCD
    const int zq  = p >> 6;                // 0..4
    const int seg = p & 63;                // 0..63
    const int z   = 5 * xcd + zq;          // image id 0..39
    const int y0  = 8 * seg;

    const float* src = (z < 24) ? outs + z * HW : labs + (z - 24) * HW;
    __half* acd = ac + z * HW;
    __half* rsd = rs + z * HW;

    const int   col = 8 * l;
    const int   aL1 = ((l - 1) & 63) << 2;
    const int   aR1 = ((l + 1) & 63) << 2;
    const float lmE = (l > 0)  ? 1.f : 0.f;
    const float rmE = (l < 63) ? 1.f : 0.f;

    float4 rgA[8], rgB[8];   // raw ring (rows r-5..r+2 at step t)
    float4 fOA[2], fOB[2];   // subtract row r-8 (2-slack fifo)
    uint4  pk[8];            // packed-fp16 ac ring (variance subtract)
    float4 VAa = {0,0,0,0}, VAb = {0,0,0,0};
    float4 Vqa = {0,0,0,0}, Vqb = {0,0,0,0};
    #pragma unroll
    for (int k = 0; k < 8; ++k) {
        rgA[k] = make_float4(0,0,0,0); rgB[k] = make_float4(0,0,0,0);
        pk[k]  = make_uint4(0,0,0,0);
    }
    fOA[0] = fOA[1] = fOB[0] = fOB[1] = make_float4(0,0,0,0);
    rgA[0] = *(const float4*)&src[rcl(y0 - 7) * WW + col];
    rgB[0] = *(const float4*)&src[rcl(y0 - 7) * WW + col + 4];
    rgA[1] = *(const float4*)&src[rcl(y0 - 6) * WW + col];
    rgB[1] = *(const float4*)&src[rcl(y0 - 6) * WW + col + 4];

    auto step = [&](const int t) {
        const int   r  = y0 - 7 + t;
        const float rm = (r >= 0 && r < HH) ? 1.f : 0.f;
        {   // VA += raw(r)  (ring slot t&7, written at t-2)
            float4 ra = rgA[t & 7], rb = rgB[t & 7];
            VAa.x += ra.x*rm; VAa.y += ra.y*rm; VAa.z += ra.z*rm; VAa.w += ra.w*rm;
            VAb.x += rb.x*rm; VAb.y += rb.y*rm; VAb.z += rb.z*rm; VAb.w += rb.w*rm;
        }
        if (t >= 8) {   // VA -= raw(r-8)  (fifo; value-identical to ring's old)
            const float rm8 = ((r - 8) >= 0 && (r - 8) < HH) ? 1.f : 0.f;
            float4 oa = fOA[t & 1], ob = fOB[t & 1];
            VAa.x -= oa.x*rm8; VAa.y -= oa.y*rm8; VAa.z -= oa.z*rm8; VAa.w -= oa.w*rm8;
            VAb.x -= ob.x*rm8; VAb.y -= ob.y*rm8; VAb.z -= ob.z*rm8; VAb.w -= ob.w*rm8;
        }
        if (t <= 20) {                        // prefetch row r+2 into (t+2)&7
            const int rn = rcl(r + 2);
            rgA[(t + 2) & 7] = *(const float4*)&src[rn * WW + col];
            rgB[(t + 2) & 7] = *(const float4*)&src[rn * WW + col + 4];
        }
        if (t >= 6 && t <= 20) {              // prefetch subtract row (r+2)-8
            const int ro = rcl(r - 6);
            fOA[t & 1] = *(const float4*)&src[ro * WW + col];
            fOB[t & 1] = *(const float4*)&src[ro * WW + col + 4];
        }
        if (t >= 8) {
            const int   c  = r - 4;
            const float cm = (c >= 0 && c < HH) ? 1.f : 0.f;
            // centered 8-wide window on VA (mean box, 64 px)
            float p1 = VAa.x, p2 = p1+VAa.y, p3 = p2+VAa.z, p4 = p3+VAa.w;
            float p5 = p4+VAb.x, p6 = p5+VAb.y, p7 = p6+VAb.z, tt = p7+VAb.w;
            float s1 = VAb.w, s2 = VAb.z+s1, s3 = VAb.y+s2;
            float L1 = bpl(aL1, s1)*lmE, L2 = bpl(aL1, s2)*lmE, L3 = bpl(aL1, s3)*lmE;
            float R1 = bpl(aR1, p1)*rmE, R2 = bpl(aR1, p2)*rmE;
            float R3 = bpl(aR1, p3)*rmE, R4 = bpl(aR1, p4)*rmE;
            // raw row c from the ring: slot (t+4)&7 == (t-4)&7 (written t-6)
            float4 rc0 = rgA[(t + 4) & 7], rc1 = rgB[(t + 4) & 7];
            float4 aL4, aH4;
            aL4.x = (rc0.x - (L3+p5)    * (1.f/64.f)) * cm;
            aL4.y = (rc0.y - (L2+p6)    * (1.f/64.f)) * cm;
            aL4.z = (rc0.z - (L1+p7)    * (1.f/64.f)) * cm;
            aL4.w = (rc0.w - tt         * (1.f/64.f)) * cm;
            aH4.x = (rc1.x - (tt-p1+R1) * (1.f/64.f)) * cm;
            aH4.y = (rc1.y - (tt-p2+R2) * (1.f/64.f)) * cm;
            aH4.z = (rc1.z - (tt-p3+R3) * (1.f/64.f)) * cm;
            aH4.w = (rc1.w - (tt-p4+R4) * (1.f/64.f)) * cm;
            uint4 pkNew = pack8(aL4, aH4);
            if (t >= 11 && t <= 18)           // store own 8 rows
                *(uint4*)&acd[c * WW + col] = pkNew;
            // variance slide on the ROUNDED values (exact telescoping)
            float4 qnL, qnH; unpack8(pkNew, qnL, qnH);
            Vqa.x += qnL.x*qnL.x; Vqa.y += qnL.y*qnL.y;
            Vqa.z += qnL.z*qnL.z; Vqa.w += qnL.w*qnL.w;
            Vqb.x += qnH.x*qnH.x; Vqb.y += qnH.y*qnH.y;
            Vqb.z += qnH.z*qnH.z; Vqb.w += qnH.w*qnH.w;
            if (t >= 16) {                    // subtract sq(ac(c-8))
                float4 oL, oH; unpack8(pk[t & 7], oL, oH);
                Vqa.x -= oL.x*oL.x; Vqa.y -= oL.y*oL.y;
                Vqa.z -= oL.z*oL.z; Vqa.w -= oL.w*oL.w;
                Vqb.x -= oH.x*oH.x; Vqb.y -= oH.y*oH.y;
                Vqb.z -= oH.z*oH.z; Vqb.w -= oH.w*oH.w;
            }
            pk[t & 7] = pkNew;
            if (t >= 15 && t <= 22) {         // emit rs at row y = c-4
                const int y = c - 4;          // y in [y0, y0+7]
                float q1 = Vqa.x, q2 = q1+Vqa.y, q3 = q2+Vqa.z, q4 = q3+Vqa.w;
                float q5 = q4+Vqb.x, q6 = q5+Vqb.y, q7 = q6+Vqb.z, qt = q7+Vqb.w;
                float z1 = Vqb.w, z2 = Vqb.z+z1, z3 = Vqb.y+z2;
                float Lq1 = bpl(aL1, z1)*lmE, Lq2 = bpl(aL1, z2)*lmE, Lq3 = bpl(aL1, z3)*lmE;
                float Rq1 = bpl(aR1, q1)*rmE, Rq2 = bpl(aR1, q2)*rmE;
                float Rq3 = bpl(aR1, q3)*rmE, Rq4 = bpl(aR1, q4)*rmE;
                float4 rL, rH;
                rL.x = fminf(__frsqrt_rn(fmaxf(Lq3+q5,    EPV)), 60000.f);
                rL.y = fminf(__frsqrt_rn(fmaxf(Lq2+q6,    EPV)), 60000.f);
                rL.z = fminf(__frsqrt_rn(fmaxf(Lq1+q7,    EPV)), 60000.f);
                rL.w = fminf(__frsqrt_rn(fmaxf(qt,        EPV)), 60000.f);
                rH.x = fminf(__frsqrt_rn(fmaxf(qt-q1+Rq1, EPV)), 60000.f);
                rH.y = fminf(__frsqrt_rn(fmaxf(qt-q2+Rq2, EPV)), 60000.f);
                rH.z = fminf(__frsqrt_rn(fmaxf(qt-q3+Rq3, EPV)), 60000.f);
                rH.w = fminf(__frsqrt_rn(fmaxf(qt-q4+Rq4, EPV)), 60000.f);
                *(uint4*)&rsd[y * WW + col] = pack8(rL, rH);
            }
        }
    };
    #pragma unroll
    for (int t = 0; t < 23; ++t) step(t);
}

// ---------------- main: product boxes, full-width rows, 4 j per wave ------
// One wave per (z, 8-row seg). 15 steps. 1536 waves, XCD-chunked.
// Vp[j] += p(row c) - p(row c-8); subtract rows via 2-slack reload (exact
// fp16 telescoping). Emit window centered (7 bp / 8 cols / j).
__global__ void __launch_bounds__(64)
__attribute__((amdgpu_waves_per_eu(2, 2)))
ncc_f8(const __half* __restrict__ ac, const __half* __restrict__ rs,
       float* __restrict__ wsum)
{
    const int l   = threadIdx.x;
    const int n   = blockIdx.x;            // 0..1535
    const int xcd = n & 7;
    const int p   = n >> 3;                // 0..191
    const int zq  = p >> 6;                // 0..2
    const int seg = p & 63;                // 0..63
    const int z   = 3 * xcd + zq;          // b*6 + i
    const int b   = z / 6;
    const int y0  = 8 * seg;

    const __half* acp = ac + z * HW;
    const __half* sip = rs + z * HW;
    const __half* bcp[4]; const __half* sjp[4];
    #pragma unroll
    for (int j = 0; j < 4; ++j) {
        bcp[j] = ac + (24 + b * 4 + j) * HW;
        sjp[j] = rs + (24 + b * 4 + j) * HW;
    }

    const int   col = 8 * l;
    const int   aL1 = ((l - 1) & 63) << 2;
    const int   aR1 = ((l + 1) & 63) << 2;
    const float lmE = (l > 0)  ? 1.f : 0.f;
    const float rmE = (l < 63) ? 1.f : 0.f;

    uint4 fa[2], fb[4][2];                 // add rows (2-slack)
    uint4 oA[2], oB[4][2];                 // subtract rows (2-slack)
    {
        const int r0 = rcl(y0 - 3), r1 = rcl(y0 - 2);
        fa[0] = *(const uint4*)&acp[r0 * WW + col];
        fa[1] = *(const uint4*)&acp[r1 * WW + col];
        #pragma unroll
        for (int j = 0; j < 4; ++j) {
            fb[j][0] = *(const uint4*)&bcp[j][r0 * WW + col];
            fb[j][1] = *(const uint4*)&bcp[j][r1 * WW + col];
            oB[j][0] = make_uint4(0,0,0,0); oB[j][1] = make_uint4(0,0,0,0);
        }
        oA[0] = make_uint4(0,0,0,0); oA[1] = make_uint4(0,0,0,0);
    }

    float4 VpL[4], VpH[4];
    uint4 psiB[2], psjB[2][4];
    float4 xsL = make_float4(0,0,0,0), xsH = make_float4(0,0,0,0);
    #pragma unroll
    for (int j = 0; j < 4; ++j) {
        VpL[j] = make_float4(0,0,0,0); VpH[j] = make_float4(0,0,0,0);
        psjB[0][j] = make_uint4(0,0,0,0); psjB[1][j] = make_uint4(0,0,0,0);
    }
    psiB[0] = make_uint4(0,0,0,0); psiB[1] = make_uint4(0,0,0,0);

    auto step = [&](const int t) {
        const int   c  = y0 - 3 + t;                 // row being ADDED
        const float rm = (c >= 0 && c < HH) ? 1.f : 0.f;
        uint4 ar = fa[t & 1];
        uint4 br0 = fb[0][t & 1], br1 = fb[1][t & 1];
        uint4 br2 = fb[2][t & 1], br3 = fb[3][t & 1];
        uint4 arO = oA[t & 1];                       // row c-8 (valid t>=8)
        uint4 bo0 = oB[0][t & 1], bo1 = oB[1][t & 1];
        uint4 bo2 = oB[2][t & 1], bo3 = oB[3][t & 1];
        if (t <= 12) {                               // add-row prefetch
            const int rn = rcl(c + 2);
            fa[t & 1] = *(const uint4*)&acp[rn * WW + col];
            #pragma unroll
            for (int j = 0; j < 4; ++j)
                fb[j][t & 1] = *(const uint4*)&bcp[j][rn * WW + col];
        }
        if (t >= 6 && t <= 12) {                     // subtract-row prefetch
            const int ro = rcl(c - 6);               // used at t+2 (row c-6)
            oA[t & 1] = *(const uint4*)&acp[ro * WW + col];
            #pragma unroll
            for (int j = 0; j < 4; ++j)
                oB[j][t & 1] = *(const uint4*)&bcp[j][ro * WW + col];
        }
        {   // add products of row c
            float4 avL, avH; unpack8(ar, avL, avH);
            avL.x *= rm; avL.y *= rm; avL.z *= rm; avL.w *= rm;
            avH.x *= rm; avH.y *= rm; avH.z *= rm; avH.w *= rm;
            float4 bL, bH;
            unpack8(br0, bL, bH);
            VpL[0].x += avL.x*bL.x; VpL[0].y += avL.y*bL.y; VpL[0].z += avL.z*bL.z; VpL[0].w += avL.w*bL.w;
            VpH[0].x += avH.x*bH.x; VpH[0].y += avH.y*bH.y; VpH[0].z += avH.z*bH.z; VpH[0].w += avH.w*bH.w;
            unpack8(br1, bL, bH);
            VpL[1].x += avL.x*bL.x; VpL[1].y += avL.y*bL.y; VpL[1].z += avL.z*bL.z; VpL[1].w += avL.w*bL.w;
            VpH[1].x += avH.x*bH.x; VpH[1].y += avH.y*bH.y; VpH[1].z += avH.z*bH.z; VpH[1].w += avH.w*bH.w;
            unpack8(br2, bL, bH);
            VpL[2].x += avL.x*bL.x; VpL[2].y += avL.y*bL.y; VpL[2].z += avL.z*bL.z; VpL[2].w += avL.w*bL.w;
            VpH[2].x += avH.x*bH.x; VpH[2].y += avH.y*bH.y; VpH[2].z += avH.z*bH.z; VpH[2].w += avH.w*bH.w;
            unpack8(br3, bL, bH);
            VpL[3].x += avL.x*bL.x; VpL[3].y += avL.y*bL.y; VpL[3].z += avL.z*bL.z; VpL[3].w += avL.w*bL.w;
            VpH[3].x += avH.x*bH.x; VpH[3].y += avH.y*bH.y; VpH[3].z += avH.z*bH.z; VpH[3].w += avH.w*bH.w;
        }
        if (t >= 8) {   // subtract products of row c-8
            const float rmO = ((c - 8) >= 0) ? 1.f : 0.f;
            float4 avL, avH; unpack8(arO, avL, avH);
            avL.x *= rmO; avL.y *= rmO; avL.z *= rmO; avL.w *= rmO;
            avH.x *= rmO; avH.y *= rmO; avH.z *= rmO; avH.w *= rmO;
            float4 bL, bH;
            unpack8(bo0, bL, bH);
            VpL[0].x -= avL.x*bL.x; VpL[0].y -= avL.y*bL.y; VpL[0].z -= avL.z*bL.z; VpL[0].w -= avL.w*bL.w;
            VpH[0].x -= avH.x*bH.x; VpH[0].y -= avH.y*bH.y; VpH[0].z -= avH.z*bH.z; VpH[0].w -= avH.w*bH.w;
            unpack8(bo1, bL, bH);
            VpL[1].x -= avL.x*bL.x; VpL[1].y -= avL.y*bL.y; VpL[1].z -= avL.z*bL.z; VpL[1].w -= avL.w*bL.w;
            VpH[1].x -= avH.x*bH.x; VpH[1].y -= avH.y*bH.y; VpH[1].z -= avH.z*bH.z; VpH[1].w -= avH.w*bH.w;
            unpack8(bo2, bL, bH);
            VpL[2].x -= avL.x*bL.x; VpL[2].y -= avL.y*bL.y; VpL[2].z -= avL.z*bL.z; VpL[2].w -= avL.w*bL.w;
            VpH[2].x -= avH.x*bH.x; VpH[2].y -= avH.y*bH.y; VpH[2].z -= avH.z*bH.z; VpH[2].w -= avH.w*bH.w;
            unpack8(bo3, bL, bH);
            VpL[3].x -= avL.x*bL.x; VpL[3].y -= avL.y*bL.y; VpL[3].z -= avL.z*bL.z; VpL[3].w -= avL.w*bL.w;
            VpH[3].x -= avH.x*bH.x; VpH[3].y -= avH.y*bH.y; VpH[3].z -= avH.z*bH.z; VpH[3].w -= avH.w*bH.w;
        }
        if (t >= 7 && t <= 14) {   // emit row y = y0+t-7 (all cols valid)
            float4 pL, pH; unpack8(psiB[t & 1], pL, pH);
            float4 mmL = make_float4(-1,-1,-1,-1), mmH = make_float4(-1,-1,-1,-1);
            #pragma unroll
            for (int j = 0; j < 4; ++j) {
                float q1 = VpL[j].x, q2 = q1+VpL[j].y, q3 = q2+VpL[j].z, q4 = q3+VpL[j].w;
                float q5 = q4+VpH[j].x, q6 = q5+VpH[j].y, q7 = q6+VpH[j].z, q8 = q7+VpH[j].w;
                float s1 = VpH[j].w, s2 = VpH[j].z+s1, s3 = VpH[j].y+s2;
                float L1 = bpl(aL1, s1)*lmE, L2 = bpl(aL1, s2)*lmE, L3 = bpl(aL1, s3)*lmE;
                float R1 = bpl(aR1, q1)*rmE, R2 = bpl(aR1, q2)*rmE;
                float R3 = bpl(aR1, q3)*rmE, R4 = bpl(aR1, q4)*rmE;
                float4 sL, sH; unpack8(psjB[t & 1][j], sL, sH);
                mmL.x = fmaxf(mmL.x, (L3+q5)    * (pL.x*sL.x));
                mmL.y = fmaxf(mmL.y, (L2+q6)    * (pL.y*sL.y));
                mmL.z = fmaxf(mmL.z, (L1+q7)    * (pL.z*sL.z));
                mmL.w = fmaxf(mmL.w, q8         * (pL.w*sL.w));
                mmH.x = fmaxf(mmH.x, (q8-q1+R1) * (pH.x*sH.x));
                mmH.y = fmaxf(mmH.y, (q8-q2+R2) * (pH.y*sH.y));
                mmH.z = fmaxf(mmH.z, (q8-q3+R3) * (pH.z*sH.z));
                mmH.w = fmaxf(mmH.w, (q8-q4+R4) * (pH.w*sH.w));
            }
            xsL.x += 1.f - fminf(mmL.x, 1.f);
            xsL.y += 1.f - fminf(mmL.y, 1.f);
            xsL.z += 1.f - fminf(mmL.z, 1.f);
            xsL.w += 1.f - fminf(mmL.w, 1.f);
            xsH.x += 1.f - fminf(mmH.x, 1.f);
            xsH.y += 1.f - fminf(mmH.y, 1.f);
            xsH.z += 1.f - fminf(mmH.z, 1.f);
            xsH.w += 1.f - fminf(mmH.w, 1.f);
        }
        if (t >= 5 && t <= 12) {   // denom prefetch, 2-step slack
            const int yn = min(y0 + t - 5, HH - 1);
            psiB[t & 1] = *(const uint4*)&sip[yn * WW + col];
            #pragma unroll
            for (int j = 0; j < 4; ++j)
                psjB[t & 1][j] = *(const uint4*)&sjp[j][yn * WW + col];
        }
    };
    #pragma unroll
    for (int t = 0; t < 15; ++t) step(t);

    float xt = xsL.x + xsL.y + xsL.z + xsL.w + xsH.x + xsH.y + xsH.z + xsH.w;
    #pragma unroll
    for (int off = 32; off > 0; off >>= 1) xt += __shfl_down(xt, off);
    if (l == 0) atomicAdd(&wsum[z * 64], xt);
}

// ---------------- finalize: 24 partials -> 25 outputs ---------------------
__global__ void fin_f4(const float* __restrict__ wsum, float* __restrict__ out)
{
    const int l = threadIdx.x;
    float v = (l < 24) ? wsum[l * 64] : 0.f;
    if (l < 24) out[1 + l] = v * (1.f / (float)HW);
    #pragma unroll
    for (int off = 32; off > 0; off >>= 1) v += __shfl_down(v, off);
    if (l == 0) out[0] = v * (1.f / (24.f * (float)HW));
}

extern "C" void kernel_launch(void* const* d_in, const int* in_sizes, int n_in,
                              void* d_out, int out_size, void* d_ws, size_t ws_size,
                              hipStream_t stream) {
    const float* outs = (const float*)d_in[0];   // (4,6,512,512)
    const float* labs = (const float*)d_in[1];   // (4,4,512,512)
    float* out = (float*)d_out;                  // 25 floats
    float* ws  = (float*)d_ws;

    __half* acw  = (__half*)ws;            // 40*HW halves (a:0..23, b:24..39)
    __half* rsw  = (__half*)ws + 40 * HW;  // 40*HW halves (fp16 1/sqrt(var))
    float*  wsum = ws + 40 * HW;           // floats: after the two half arrays

    // prep: 2560 blocks (40 z x 64 segs of 8 rows), XCD-chunked decode
    prep_f8<<<dim3(2560, 1, 1), 64, 0, stream>>>(outs, labs, acw, rsw, wsum);
    // main: 1536 blocks (24 z x 64 segs of 8 rows), XCD-chunked decode
    ncc_f8<<<dim3(1536, 1, 1), 64, 0, stream>>>(acw, rsw, wsum);
    // finalize: one wave
    fin_f4<<<dim3(1, 1, 1), 64, 0, stream>>>(wsum, out);
}

// Round 13
// 134.870 us; speedup vs baseline: 1.2008x; 1.0373x over previous
//
#include <hip/hip_runtime.h>
#include <hip/hip_fp16.h>

#define HH 512
#define WW 512
#define HW (HH*WW)
#define EPV 1e-20f

// R22 = R19 prep (XCD-chunk reverted: R21 showed chunking helps only ops
// with cross-block operand reuse -- ncc's shared b-panels -- not streaming
// producers; prep FETCH dropped but dur rose 42.6->54.6) + ncc 4-row segs.
// Step-count law (R15: 26->15 steps = 69->49.5us): ncc 15->11 steps via
// y0=4*seg, 128 segs, 3072 blocks = 12/CU, pin waves_per_eu(3,3) (VGPR<=170;
// live ~155 after trimming sub fifo to 1-slack, R18-proven).
// Keeps: 8-col centered windows (7bp/8cols), fp16 intermediates, exact
// telescoping, XCD-chunked ncc, per-z wsum + fin, barrier-free.

__device__ __forceinline__ float bpl(int addr, float v) {
    return __int_as_float(__builtin_amdgcn_ds_bpermute(addr, __float_as_int(v)));
}
__device__ __forceinline__ int rcl(int r) { return min(max(r, 0), HH - 1); }

__device__ __forceinline__ float4 h2f4(uint2 r) {
    __half2 lo = *(__half2*)&r.x, hi = *(__half2*)&r.y;
    float2 a = __half22float2(lo), b = __half22float2(hi);
    return make_float4(a.x, a.y, b.x, b.y);
}
__device__ __forceinline__ uint2 f2h4(float4 v) {
    __half2 lo = __floats2half2_rn(v.x, v.y);
    __half2 hi = __floats2half2_rn(v.z, v.w);
    uint2 r;
    r.x = *(unsigned int*)&lo;
    r.y = *(unsigned int*)&hi;
    return r;
}
__device__ __forceinline__ uint4 pack8(float4 a, float4 b) {
    uint2 lo = f2h4(a), hi = f2h4(b);
    return make_uint4(lo.x, lo.y, hi.x, hi.y);
}
__device__ __forceinline__ void unpack8(uint4 r, float4& a, float4& b) {
    a = h2f4(make_uint2(r.x, r.y));
    b = h2f4(make_uint2(r.z, r.w));
}

// ---------------- prep: raw -> fp16 centered (ac) + fp16 1/sqrt(var box) --
// One wave per (z, 8-row seg), full 512-col rows. 23 steps. R19 grid
// (64 segs x 40 images, default dispatch -- chunking regressed, R21).
// r = y0-7+t (VA add row), c = r-4 (ac row), y = c-4 (rs row).
// Raw ring rg[8]: slot t&7 = row r (written at t-2); center = slot (t+4)&7.
__global__ void __launch_bounds__(64)
__attribute__((amdgpu_waves_per_eu(3, 3)))
prep_f8(const float* __restrict__ outs, const float* __restrict__ labs,
        __half* __restrict__ ac, __half* __restrict__ rs,
        float* __restrict__ wsum)
{
    const int l = threadIdx.x;
    if (blockIdx.x == 0 && blockIdx.y == 0 && l < 24)
        wsum[l * 64] = 0.f;                   // zero per-z partial slots
    const int y0 = 8 * blockIdx.x;
    const int z  = blockIdx.y;

    const float* src = (z < 24) ? outs + z * HW : labs + (z - 24) * HW;
    __half* acd = ac + z * HW;
    __half* rsd = rs + z * HW;

    const int   col = 8 * l;
    const int   aL1 = ((l - 1) & 63) << 2;
    const int   aR1 = ((l + 1) & 63) << 2;
    const float lmE = (l > 0)  ? 1.f : 0.f;
    const float rmE = (l < 63) ? 1.f : 0.f;

    float4 rgA[8], rgB[8];   // raw ring (rows r-5..r+2 at step t)
    float4 fOA[2], fOB[2];   // subtract row r-8 (2-slack fifo)
    uint4  pk[8];            // packed-fp16 ac ring (variance subtract)
    float4 VAa = {0,0,0,0}, VAb = {0,0,0,0};
    float4 Vqa = {0,0,0,0}, Vqb = {0,0,0,0};
    #pragma unroll
    for (int k = 0; k < 8; ++k) {
        rgA[k] = make_float4(0,0,0,0); rgB[k] = make_float4(0,0,0,0);
        pk[k]  = make_uint4(0,0,0,0);
    }
    fOA[0] = fOA[1] = fOB[0] = fOB[1] = make_float4(0,0,0,0);
    rgA[0] = *(const float4*)&src[rcl(y0 - 7) * WW + col];
    rgB[0] = *(const float4*)&src[rcl(y0 - 7) * WW + col + 4];
    rgA[1] = *(const float4*)&src[rcl(y0 - 6) * WW + col];
    rgB[1] = *(const float4*)&src[rcl(y0 - 6) * WW + col + 4];

    auto step = [&](const int t) {
        const int   r  = y0 - 7 + t;
        const float rm = (r >= 0 && r < HH) ? 1.f : 0.f;
        {   // VA += raw(r)  (ring slot t&7, written at t-2)
            float4 ra = rgA[t & 7], rb = rgB[t & 7];
            VAa.x += ra.x*rm; VAa.y += ra.y*rm; VAa.z += ra.z*rm; VAa.w += ra.w*rm;
            VAb.x += rb.x*rm; VAb.y += rb.y*rm; VAb.z += rb.z*rm; VAb.w += rb.w*rm;
        }
        if (t >= 8) {   // VA -= raw(r-8)  (fifo; value-identical to ring's old)
            const float rm8 = ((r - 8) >= 0 && (r - 8) < HH) ? 1.f : 0.f;
            float4 oa = fOA[t & 1], ob = fOB[t & 1];
            VAa.x -= oa.x*rm8; VAa.y -= oa.y*rm8; VAa.z -= oa.z*rm8; VAa.w -= oa.w*rm8;
            VAb.x -= ob.x*rm8; VAb.y -= ob.y*rm8; VAb.z -= ob.z*rm8; VAb.w -= ob.w*rm8;
        }
        if (t <= 20) {                        // prefetch row r+2 into (t+2)&7
            const int rn = rcl(r + 2);
            rgA[(t + 2) & 7] = *(const float4*)&src[rn * WW + col];
            rgB[(t + 2) & 7] = *(const float4*)&src[rn * WW + col + 4];
        }
        if (t >= 6 && t <= 20) {              // prefetch subtract row (r+2)-8
            const int ro = rcl(r - 6);
            fOA[t & 1] = *(const float4*)&src[ro * WW + col];
            fOB[t & 1] = *(const float4*)&src[ro * WW + col + 4];
        }
        if (t >= 8) {
            const int   c  = r - 4;
            const float cm = (c >= 0 && c < HH) ? 1.f : 0.f;
            // centered 8-wide window on VA (mean box, 64 px)
            float p1 = VAa.x, p2 = p1+VAa.y, p3 = p2+VAa.z, p4 = p3+VAa.w;
            float p5 = p4+VAb.x, p6 = p5+VAb.y, p7 = p6+VAb.z, tt = p7+VAb.w;
            float s1 = VAb.w, s2 = VAb.z+s1, s3 = VAb.y+s2;
            float L1 = bpl(aL1, s1)*lmE, L2 = bpl(aL1, s2)*lmE, L3 = bpl(aL1, s3)*lmE;
            float R1 = bpl(aR1, p1)*rmE, R2 = bpl(aR1, p2)*rmE;
            float R3 = bpl(aR1, p3)*rmE, R4 = bpl(aR1, p4)*rmE;
            // raw row c from the ring: slot (t+4)&7 == (t-4)&7 (written t-6)
            float4 rc0 = rgA[(t + 4) & 7], rc1 = rgB[(t + 4) & 7];
            float4 aL4, aH4;
            aL4.x = (rc0.x - (L3+p5)    * (1.f/64.f)) * cm;
            aL4.y = (rc0.y - (L2+p6)    * (1.f/64.f)) * cm;
            aL4.z = (rc0.z - (L1+p7)    * (1.f/64.f)) * cm;
            aL4.w = (rc0.w - tt         * (1.f/64.f)) * cm;
            aH4.x = (rc1.x - (tt-p1+R1) * (1.f/64.f)) * cm;
            aH4.y = (rc1.y - (tt-p2+R2) * (1.f/64.f)) * cm;
            aH4.z = (rc1.z - (tt-p3+R3) * (1.f/64.f)) * cm;
            aH4.w = (rc1.w - (tt-p4+R4) * (1.f/64.f)) * cm;
            uint4 pkNew = pack8(aL4, aH4);
            if (t >= 11 && t <= 18)           // store own 8 rows
                *(uint4*)&acd[c * WW + col] = pkNew;
            // variance slide on the ROUNDED values (exact telescoping)
            float4 qnL, qnH; unpack8(pkNew, qnL, qnH);
            Vqa.x += qnL.x*qnL.x; Vqa.y += qnL.y*qnL.y;
            Vqa.z += qnL.z*qnL.z; Vqa.w += qnL.w*qnL.w;
            Vqb.x += qnH.x*qnH.x; Vqb.y += qnH.y*qnH.y;
            Vqb.z += qnH.z*qnH.z; Vqb.w += qnH.w*qnH.w;
            if (t >= 16) {                    // subtract sq(ac(c-8))
                float4 oL, oH; unpack8(pk[t & 7], oL, oH);
                Vqa.x -= oL.x*oL.x; Vqa.y -= oL.y*oL.y;
                Vqa.z -= oL.z*oL.z; Vqa.w -= oL.w*oL.w;
                Vqb.x -= oH.x*oH.x; Vqb.y -= oH.y*oH.y;
                Vqb.z -= oH.z*oH.z; Vqb.w -= oH.w*oH.w;
            }
            pk[t & 7] = pkNew;
            if (t >= 15 && t <= 22) {         // emit rs at row y = c-4
                const int y = c - 4;          // y in [y0, y0+7]
                float q1 = Vqa.x, q2 = q1+Vqa.y, q3 = q2+Vqa.z, q4 = q3+Vqa.w;
                float q5 = q4+Vqb.x, q6 = q5+Vqb.y, q7 = q6+Vqb.z, qt = q7+Vqb.w;
                float z1 = Vqb.w, z2 = Vqb.z+z1, z3 = Vqb.y+z2;
                float Lq1 = bpl(aL1, z1)*lmE, Lq2 = bpl(aL1, z2)*lmE, Lq3 = bpl(aL1, z3)*lmE;
                float Rq1 = bpl(aR1, q1)*rmE, Rq2 = bpl(aR1, q2)*rmE;
                float Rq3 = bpl(aR1, q3)*rmE, Rq4 = bpl(aR1, q4)*rmE;
                float4 rL, rH;
                rL.x = fminf(__frsqrt_rn(fmaxf(Lq3+q5,    EPV)), 60000.f);
                rL.y = fminf(__frsqrt_rn(fmaxf(Lq2+q6,    EPV)), 60000.f);
                rL.z = fminf(__frsqrt_rn(fmaxf(Lq1+q7,    EPV)), 60000.f);
                rL.w = fminf(__frsqrt_rn(fmaxf(qt,        EPV)), 60000.f);
                rH.x = fminf(__frsqrt_rn(fmaxf(qt-q1+Rq1, EPV)), 60000.f);
                rH.y = fminf(__frsqrt_rn(fmaxf(qt-q2+Rq2, EPV)), 60000.f);
                rH.z = fminf(__frsqrt_rn(fmaxf(qt-q3+Rq3, EPV)), 60000.f);
                rH.w = fminf(__frsqrt_rn(fmaxf(qt-q4+Rq4, EPV)), 60000.f);
                *(uint4*)&rsd[y * WW + col] = pack8(rL, rH);
            }
        }
    };
    #pragma unroll
    for (int t = 0; t < 23; ++t) step(t);
}

// ---------------- main: product boxes, 4-row segs, 11 steps ---------------
// One wave per (z, 4-row seg). 3072 waves = 12/CU @ waves_per_eu(3,3).
// XCD-chunked: XCD k owns z in {3k,3k+1,3k+2}. Steps t=0..10: add row
// c=y0-3+t (2-slack); subtract row c-8 for t>=8 (1-slack); emit row
// y0+t-7 for t>=7 (psi 2-slack). Exact fp16 telescoping.
__global__ void __launch_bounds__(64)
__attribute__((amdgpu_waves_per_eu(3, 3)))
ncc_f8(const __half* __restrict__ ac, const __half* __restrict__ rs,
       float* __restrict__ wsum)
{
    const int l   = threadIdx.x;
    const int n   = blockIdx.x;            // 0..3071
    const int xcd = n & 7;
    const int p   = n >> 3;                // 0..383
    const int zq  = p >> 7;                // 0..2
    const int seg = p & 127;               // 0..127
    const int z   = 3 * xcd + zq;          // b*6 + i
    const int b   = z / 6;
    const int y0  = 4 * seg;

    const __half* acp = ac + z * HW;
    const __half* sip = rs + z * HW;
    const __half* bcp[4]; const __half* sjp[4];
    #pragma unroll
    for (int j = 0; j < 4; ++j) {
        bcp[j] = ac + (24 + b * 4 + j) * HW;
        sjp[j] = rs + (24 + b * 4 + j) * HW;
    }

    const int   col = 8 * l;
    const int   aL1 = ((l - 1) & 63) << 2;
    const int   aR1 = ((l + 1) & 63) << 2;
    const float lmE = (l > 0)  ? 1.f : 0.f;
    const float rmE = (l < 63) ? 1.f : 0.f;

    uint4 fa[2], fb[4][2];                 // add rows (2-slack)
    uint4 oA, oB[4];                       // subtract row (1-slack)
    {
        const int r0 = rcl(y0 - 3), r1 = rcl(y0 - 2);
        fa[0] = *(const uint4*)&acp[r0 * WW + col];
        fa[1] = *(const uint4*)&acp[r1 * WW + col];
        #pragma unroll
        for (int j = 0; j < 4; ++j) {
            fb[j][0] = *(const uint4*)&bcp[j][r0 * WW + col];
            fb[j][1] = *(const uint4*)&bcp[j][r1 * WW + col];
            oB[j] = make_uint4(0,0,0,0);
        }
        oA = make_uint4(0,0,0,0);
    }

    float4 VpL[4], VpH[4];
    uint4 psiB[2], psjB[2][4];
    float4 xsL = make_float4(0,0,0,0), xsH = make_float4(0,0,0,0);
    #pragma unroll
    for (int j = 0; j < 4; ++j) {
        VpL[j] = make_float4(0,0,0,0); VpH[j] = make_float4(0,0,0,0);
        psjB[0][j] = make_uint4(0,0,0,0); psjB[1][j] = make_uint4(0,0,0,0);
    }
    psiB[0] = make_uint4(0,0,0,0); psiB[1] = make_uint4(0,0,0,0);

    auto step = [&](const int t) {
        const int   c  = y0 - 3 + t;                 // row being ADDED
        const float rm = (c >= 0 && c < HH) ? 1.f : 0.f;
        uint4 ar = fa[t & 1];
        uint4 br0 = fb[0][t & 1], br1 = fb[1][t & 1];
        uint4 br2 = fb[2][t & 1], br3 = fb[3][t & 1];
        uint4 arO = oA;                              // row c-8 (valid t>=8)
        uint4 bo0 = oB[0], bo1 = oB[1], bo2 = oB[2], bo3 = oB[3];
        if (t <= 8) {                                // add-row prefetch (t+2)
            const int rn = rcl(c + 2);
            fa[t & 1] = *(const uint4*)&acp[rn * WW + col];
            #pragma unroll
            for (int j = 0; j < 4; ++j)
                fb[j][t & 1] = *(const uint4*)&bcp[j][rn * WW + col];
        }
        if (t >= 7 && t <= 9) {                      // sub-row prefetch (t+1)
            const int ro = rcl(c - 7);               // = (c+1)-8
            oA = *(const uint4*)&acp[ro * WW + col];
            #pragma unroll
            for (int j = 0; j < 4; ++j)
                oB[j] = *(const uint4*)&bcp[j][ro * WW + col];
        }
        {   // add products of row c
            float4 avL, avH; unpack8(ar, avL, avH);
            avL.x *= rm; avL.y *= rm; avL.z *= rm; avL.w *= rm;
            avH.x *= rm; avH.y *= rm; avH.z *= rm; avH.w *= rm;
            float4 bL, bH;
            unpack8(br0, bL, bH);
            VpL[0].x += avL.x*bL.x; VpL[0].y += avL.y*bL.y; VpL[0].z += avL.z*bL.z; VpL[0].w += avL.w*bL.w;
            VpH[0].x += avH.x*bH.x; VpH[0].y += avH.y*bH.y; VpH[0].z += avH.z*bH.z; VpH[0].w += avH.w*bH.w;
            unpack8(br1, bL, bH);
            VpL[1].x += avL.x*bL.x; VpL[1].y += avL.y*bL.y; VpL[1].z += avL.z*bL.z; VpL[1].w += avL.w*bL.w;
            VpH[1].x += avH.x*bH.x; VpH[1].y += avH.y*bH.y; VpH[1].z += avH.z*bH.z; VpH[1].w += avH.w*bH.w;
            unpack8(br2, bL, bH);
            VpL[2].x += avL.x*bL.x; VpL[2].y += avL.y*bL.y; VpL[2].z += avL.z*bL.z; VpL[2].w += avL.w*bL.w;
            VpH[2].x += avH.x*bH.x; VpH[2].y += avH.y*bH.y; VpH[2].z += avH.z*bH.z; VpH[2].w += avH.w*bH.w;
            unpack8(br3, bL, bH);
            VpL[3].x += avL.x*bL.x; VpL[3].y += avL.y*bL.y; VpL[3].z += avL.z*bL.z; VpL[3].w += avL.w*bL.w;
            VpH[3].x += avH.x*bH.x; VpH[3].y += avH.y*bH.y; VpH[3].z += avH.z*bH.z; VpH[3].w += avH.w*bH.w;
        }
        if (t >= 8) {   // subtract products of row c-8 (loaded last step)
            const float rmO = ((c - 8) >= 0) ? 1.f : 0.f;
            float4 avL, avH; unpack8(arO, avL, avH);
            avL.x *= rmO; avL.y *= rmO; avL.z *= rmO; avL.w *= rmO;
            avH.x *= rmO; avH.y *= rmO; avH.z *= rmO; avH.w *= rmO;
            float4 bL, bH;
            unpack8(bo0, bL, bH);
            VpL[0].x -= avL.x*bL.x; VpL[0].y -= avL.y*bL.y; VpL[0].z -= avL.z*bL.z; VpL[0].w -= avL.w*bL.w;
            VpH[0].x -= avH.x*bH.x; VpH[0].y -= avH.y*bH.y; VpH[0].z -= avH.z*bH.z; VpH[0].w -= avH.w*bH.w;
            unpack8(bo1, bL, bH);
            VpL[1].x -= avL.x*bL.x; VpL[1].y -= avL.y*bL.y; VpL[1].z -= avL.z*bL.z; VpL[1].w -= avL.w*bL.w;
            VpH[1].x -= avH.x*bH.x; VpH[1].y -= avH.y*bH.y; VpH[1].z -= avH.z*bH.z; VpH[1].w -= avH.w*bH.w;
            unpack8(bo2, bL, bH);
            VpL[2].x -= avL.x*bL.x; VpL[2].y -= avL.y*bL.y; VpL[2].z -= avL.z*bL.z; VpL[2].w -= avL.w*bL.w;
            VpH[2].x -= avH.x*bH.x; VpH[2].y -= avH.y*bH.y; VpH[2].z -= avH.z*bH.z; VpH[2].w -= avH.w*bH.w;
            unpack8(bo3, bL, bH);
            VpL[3].x -= avL.x*bL.x; VpL[3].y -= avL.y*bL.y; VpL[3].z -= avL.z*bL.z; VpL[3].w -= avL.w*bL.w;
            VpH[3].x -= avH.x*bH.x; VpH[3].y -= avH.y*bH.y; VpH[3].z -= avH.z*bH.z; VpH[3].w -= avH.w*bH.w;
        }
        if (t >= 7) {   // emit row y = y0+t-7 (in [y0, y0+3], always valid)
            float4 pL, pH; unpack8(psiB[t & 1], pL, pH);
            float4 mmL = make_float4(-1,-1,-1,-1), mmH = make_float4(-1,-1,-1,-1);
            #pragma unroll
            for (int j = 0; j < 4; ++j) {
                float q1 = VpL[j].x, q2 = q1+VpL[j].y, q3 = q2+VpL[j].z, q4 = q3+VpL[j].w;
                float q5 = q4+VpH[j].x, q6 = q5+VpH[j].y, q7 = q6+VpH[j].z, q8 = q7+VpH[j].w;
                float s1 = VpH[j].w, s2 = VpH[j].z+s1, s3 = VpH[j].y+s2;
                float L1 = bpl(aL1, s1)*lmE, L2 = bpl(aL1, s2)*lmE, L3 = bpl(aL1, s3)*lmE;
                float R1 = bpl(aR1, q1)*rmE, R2 = bpl(aR1, q2)*rmE;
                float R3 = bpl(aR1, q3)*rmE, R4 = bpl(aR1, q4)*rmE;
                float4 sL, sH; unpack8(psjB[t & 1][j], sL, sH);
                mmL.x = fmaxf(mmL.x, (L3+q5)    * (pL.x*sL.x));
                mmL.y = fmaxf(mmL.y, (L2+q6)    * (pL.y*sL.y));
                mmL.z = fmaxf(mmL.z, (L1+q7)    * (pL.z*sL.z));
                mmL.w = fmaxf(mmL.w, q8         * (pL.w*sL.w));
                mmH.x = fmaxf(mmH.x, (q8-q1+R1) * (pH.x*sH.x));
                mmH.y = fmaxf(mmH.y, (q8-q2+R2) * (pH.y*sH.y));
                mmH.z = fmaxf(mmH.z, (q8-q3+R3) * (pH.z*sH.z));
                mmH.w = fmaxf(mmH.w, (q8-q4+R4) * (pH.w*sH.w));
            }
            xsL.x += 1.f - fminf(mmL.x, 1.f);
            xsL.y += 1.f - fminf(mmL.y, 1.f);
            xsL.z += 1.f - fminf(mmL.z, 1.f);
            xsL.w += 1.f - fminf(mmL.w, 1.f);
            xsH.x += 1.f - fminf(mmH.x, 1.f);
            xsH.y += 1.f - fminf(mmH.y, 1.f);
            xsH.z += 1.f - fminf(mmH.z, 1.f);
            xsH.w += 1.f - fminf(mmH.w, 1.f);
        }
        if (t >= 5 && t <= 8) {   // denom prefetch (t+2), rows y0..y0+3
            const int yn = y0 + t - 5;
            psiB[t & 1] = *(const uint4*)&sip[yn * WW + col];
            #pragma unroll
            for (int j = 0; j < 4; ++j)
                psjB[t & 1][j] = *(const uint4*)&sjp[j][yn * WW + col];
        }
    };
    #pragma unroll
    for (int t = 0; t < 11; ++t) step(t);

    float xt = xsL.x + xsL.y + xsL.z + xsL.w + xsH.x + xsH.y + xsH.z + xsH.w;
    #pragma unroll
    for (int off = 32; off > 0; off >>= 1) xt += __shfl_down(xt, off);
    if (l == 0) atomicAdd(&wsum[z * 64], xt);
}

// ---------------- finalize: 24 partials -> 25 outputs ---------------------
__global__ void fin_f4(const float* __restrict__ wsum, float* __restrict__ out)
{
    const int l = threadIdx.x;
    float v = (l < 24) ? wsum[l * 64] : 0.f;
    if (l < 24) out[1 + l] = v * (1.f / (float)HW);
    #pragma unroll
    for (int off = 32; off > 0; off >>= 1) v += __shfl_down(v, off);
    if (l == 0) out[0] = v * (1.f / (24.f * (float)HW));
}

extern "C" void kernel_launch(void* const* d_in, const int* in_sizes, int n_in,
                              void* d_out, int out_size, void* d_ws, size_t ws_size,
                              hipStream_t stream) {
    const float* outs = (const float*)d_in[0];   // (4,6,512,512)
    const float* labs = (const float*)d_in[1];   // (4,4,512,512)
    float* out = (float*)d_out;                  // 25 floats
    float* ws  = (float*)d_ws;

    __half* acw  = (__half*)ws;            // 40*HW halves (a:0..23, b:24..39)
    __half* rsw  = (__half*)ws + 40 * HW;  // 40*HW halves (fp16 1/sqrt(var))
    float*  wsum = ws + 40 * HW;           // floats: after the two half arrays

    // prep: 64 segs(8 rows) x 40 images (R19 grid; also zeroes wsum)
    prep_f8<<<dim3(64, 40), 64, 0, stream>>>(outs, labs, acw, rsw, wsum);
    // main: 3072 blocks (24 z x 128 segs of 4 rows), XCD-chunked decode
    ncc_f8<<<dim3(3072, 1, 1), 64, 0, stream>>>(acw, rsw, wsum);
    // finalize: one wave
    fin_f4<<<dim3(1, 1, 1), 64, 0, stream>>>(wsum, out);
}

// Round 14
// 112.548 us; speedup vs baseline: 1.4389x; 1.1983x over previous
//
#include <hip/hip_runtime.h>
#include <hip/hip_fp16.h>

#define HH 512
#define WW 512
#define HW (HH*WW)
#define EPV 1e-20f

// R23: ncc reverted to R19's 8-row/15-step form (R22 proved 4-row segs
// raise total wave-steps +47% for -27% steps/wave = net loss; law: wall ~
// total wave-steps x per-step cost once residency >= ~6/CU). prep moves to
// the both-factors-better point: 16-row segs + depth-13 packed-fp16 raw
// ring = 39.7K wave-steps (-33%) AND one load-pair/step (-50%; ring serves
// add r, center r-4, subtract r-8 from one load). R20's spill root-caused
// to the (3,3) 170-reg cap -- pinned (2,2) here (256 budget, ~150 live,
// R18-proven). fp16 ring numerics proven by R20 (absmax 0.0; add/sub use
// identical rounded values -> exact telescoping).
// Keeps: 8-col centered windows (7bp/8cols), fp16 intermediates,
// XCD-chunked ncc, per-z wsum + fin, barrier-free.

__device__ __forceinline__ float bpl(int addr, float v) {
    return __int_as_float(__builtin_amdgcn_ds_bpermute(addr, __float_as_int(v)));
}
__device__ __forceinline__ int rcl(int r) { return min(max(r, 0), HH - 1); }

__device__ __forceinline__ float4 h2f4(uint2 r) {
    __half2 lo = *(__half2*)&r.x, hi = *(__half2*)&r.y;
    float2 a = __half22float2(lo), b = __half22float2(hi);
    return make_float4(a.x, a.y, b.x, b.y);
}
__device__ __forceinline__ uint2 f2h4(float4 v) {
    __half2 lo = __floats2half2_rn(v.x, v.y);
    __half2 hi = __floats2half2_rn(v.z, v.w);
    uint2 r;
    r.x = *(unsigned int*)&lo;
    r.y = *(unsigned int*)&hi;
    return r;
}
__device__ __forceinline__ uint4 pack8(float4 a, float4 b) {
    uint2 lo = f2h4(a), hi = f2h4(b);
    return make_uint4(lo.x, lo.y, hi.x, hi.y);
}
__device__ __forceinline__ void unpack8(uint4 r, float4& a, float4& b) {
    a = h2f4(make_uint2(r.x, r.y));
    b = h2f4(make_uint2(r.z, r.w));
}

// ---------------- prep: raw -> fp16 centered (ac) + fp16 1/sqrt(var box) --
// One wave per (z, 16-row seg), full 512-col rows. 31 steps, 1280 waves.
// r = y0-7+t (VA add row), c = r-4 (ac row), y = c-4 (rs row).
// Packed-fp16 raw ring rg[13]: slot t%13 = row r (prefetched 3 ahead into
// slot (t+3)%13); center row c = slot (t-4)%13; subtract r-8 = (t-8)%13.
// Rows in flight r-8..r+3 = 12 < 13 (no slot collision: write-read gap 11).
__global__ void __launch_bounds__(64)
__attribute__((amdgpu_waves_per_eu(2, 2)))
prep_f8(const float* __restrict__ outs, const float* __restrict__ labs,
        __half* __restrict__ ac, __half* __restrict__ rs,
        float* __restrict__ wsum)
{
    const int l = threadIdx.x;
    if (blockIdx.x == 0 && blockIdx.y == 0 && l < 24)
        wsum[l * 64] = 0.f;                   // zero per-z partial slots
    const int y0 = 16 * blockIdx.x;
    const int z  = blockIdx.y;

    const float* src = (z < 24) ? outs + z * HW : labs + (z - 24) * HW;
    __half* acd = ac + z * HW;
    __half* rsd = rs + z * HW;

    const int   col = 8 * l;
    const int   aL1 = ((l - 1) & 63) << 2;
    const int   aR1 = ((l + 1) & 63) << 2;
    const float lmE = (l > 0)  ? 1.f : 0.f;
    const float rmE = (l < 63) ? 1.f : 0.f;

    auto ldpack = [&](int row) {
        float4 a = *(const float4*)&src[row * WW + col];
        float4 b = *(const float4*)&src[row * WW + col + 4];
        return pack8(a, b);
    };

    uint4 rg[13];            // packed-fp16 raw ring
    uint4 pk[8];             // packed-fp16 ac ring (variance subtract)
    float4 VAa = {0,0,0,0}, VAb = {0,0,0,0};
    float4 Vqa = {0,0,0,0}, Vqb = {0,0,0,0};
    #pragma unroll
    for (int k = 0; k < 13; ++k) rg[k] = make_uint4(0,0,0,0);
    #pragma unroll
    for (int k = 0; k < 8; ++k) pk[k] = make_uint4(0,0,0,0);
    // preload slots 0..2 = rows y0-7..y0-5 (adds at t=0,1,2)
    rg[0] = ldpack(rcl(y0 - 7));
    rg[1] = ldpack(rcl(y0 - 6));
    rg[2] = ldpack(rcl(y0 - 5));

    auto step = [&](const int t) {
        const int   r  = y0 - 7 + t;
        const float rm = (r >= 0 && r < HH) ? 1.f : 0.f;
        {   // VA += raw(r), ring slot t%13 (prefetched at t-3 / preloaded)
            float4 ra, rb; unpack8(rg[t % 13], ra, rb);
            VAa.x += ra.x*rm; VAa.y += ra.y*rm; VAa.z += ra.z*rm; VAa.w += ra.w*rm;
            VAb.x += rb.x*rm; VAb.y += rb.y*rm; VAb.z += rb.z*rm; VAb.w += rb.w*rm;
        }
        if (t >= 8) {   // VA -= raw(r-8), slot (t-8)%13 (identical values)
            const float rm8 = ((r - 8) >= 0 && (r - 8) < HH) ? 1.f : 0.f;
            float4 oa, ob; unpack8(rg[(t - 8) % 13], oa, ob);
            VAa.x -= oa.x*rm8; VAa.y -= oa.y*rm8; VAa.z -= oa.z*rm8; VAa.w -= oa.w*rm8;
            VAb.x -= ob.x*rm8; VAb.y -= ob.y*rm8; VAb.z -= ob.z*rm8; VAb.w -= ob.w*rm8;
        }
        if (t <= 27) {  // prefetch row r+3 = y0-4+t into slot (t+3)%13
            rg[(t + 3) % 13] = ldpack(rcl(y0 - 4 + t));
        }
        if (t >= 8) {
            const int   c  = r - 4;
            const float cm = (c >= 0 && c < HH) ? 1.f : 0.f;
            // centered 8-wide window on VA (mean box, 64 px)
            float p1 = VAa.x, p2 = p1+VAa.y, p3 = p2+VAa.z, p4 = p3+VAa.w;
            float p5 = p4+VAb.x, p6 = p5+VAb.y, p7 = p6+VAb.z, tt = p7+VAb.w;
            float s1 = VAb.w, s2 = VAb.z+s1, s3 = VAb.y+s2;
            float L1 = bpl(aL1, s1)*lmE, L2 = bpl(aL1, s2)*lmE, L3 = bpl(aL1, s3)*lmE;
            float R1 = bpl(aR1, p1)*rmE, R2 = bpl(aR1, p2)*rmE;
            float R3 = bpl(aR1, p3)*rmE, R4 = bpl(aR1, p4)*rmE;
            // raw row c from ring slot (t-4)%13 (written at t-7)
            float4 rc0, rc1; unpack8(rg[(t - 4) % 13], rc0, rc1);
            float4 aL4, aH4;
            aL4.x = (rc0.x - (L3+p5)    * (1.f/64.f)) * cm;
            aL4.y = (rc0.y - (L2+p6)    * (1.f/64.f)) * cm;
            aL4.z = (rc0.z - (L1+p7)    * (1.f/64.f)) * cm;
            aL4.w = (rc0.w - tt         * (1.f/64.f)) * cm;
            aH4.x = (rc1.x - (tt-p1+R1) * (1.f/64.f)) * cm;
            aH4.y = (rc1.y - (tt-p2+R2) * (1.f/64.f)) * cm;
            aH4.z = (rc1.z - (tt-p3+R3) * (1.f/64.f)) * cm;
            aH4.w = (rc1.w - (tt-p4+R4) * (1.f/64.f)) * cm;
            uint4 pkNew = pack8(aL4, aH4);
            if (t >= 11 && t <= 26)           // store own 16 rows (c in [y0,y0+15])
                *(uint4*)&acd[c * WW + col] = pkNew;
            // variance slide on the ROUNDED values (exact telescoping)
            float4 qnL, qnH; unpack8(pkNew, qnL, qnH);
            Vqa.x += qnL.x*qnL.x; Vqa.y += qnL.y*qnL.y;
            Vqa.z += qnL.z*qnL.z; Vqa.w += qnL.w*qnL.w;
            Vqb.x += qnH.x*qnH.x; Vqb.y += qnH.y*qnH.y;
            Vqb.z += qnH.z*qnH.z; Vqb.w += qnH.w*qnH.w;
            if (t >= 16) {                    // subtract sq(ac(c-8))
                float4 oL, oH; unpack8(pk[t & 7], oL, oH);
                Vqa.x -= oL.x*oL.x; Vqa.y -= oL.y*oL.y;
                Vqa.z -= oL.z*oL.z; Vqa.w -= oL.w*oL.w;
                Vqb.x -= oH.x*oH.x; Vqb.y -= oH.y*oH.y;
                Vqb.z -= oH.z*oH.z; Vqb.w -= oH.w*oH.w;
            }
            pk[t & 7] = pkNew;
            if (t >= 15 && t <= 30) {         // emit rs at row y = c-4
                const int y = c - 4;          // y in [y0, y0+15]
                float q1 = Vqa.x, q2 = q1+Vqa.y, q3 = q2+Vqa.z, q4 = q3+Vqa.w;
                float q5 = q4+Vqb.x, q6 = q5+Vqb.y, q7 = q6+Vqb.z, qt = q7+Vqb.w;
                float z1 = Vqb.w, z2 = Vqb.z+z1, z3 = Vqb.y+z2;
                float Lq1 = bpl(aL1, z1)*lmE, Lq2 = bpl(aL1, z2)*lmE, Lq3 = bpl(aL1, z3)*lmE;
                float Rq1 = bpl(aR1, q1)*rmE, Rq2 = bpl(aR1, q2)*rmE;
                float Rq3 = bpl(aR1, q3)*rmE, Rq4 = bpl(aR1, q4)*rmE;
                float4 rL, rH;
                rL.x = fminf(__frsqrt_rn(fmaxf(Lq3+q5,    EPV)), 60000.f);
                rL.y = fminf(__frsqrt_rn(fmaxf(Lq2+q6,    EPV)), 60000.f);
                rL.z = fminf(__frsqrt_rn(fmaxf(Lq1+q7,    EPV)), 60000.f);
                rL.w = fminf(__frsqrt_rn(fmaxf(qt,        EPV)), 60000.f);
                rH.x = fminf(__frsqrt_rn(fmaxf(qt-q1+Rq1, EPV)), 60000.f);
                rH.y = fminf(__frsqrt_rn(fmaxf(qt-q2+Rq2, EPV)), 60000.f);
                rH.z = fminf(__frsqrt_rn(fmaxf(qt-q3+Rq3, EPV)), 60000.f);
                rH.w = fminf(__frsqrt_rn(fmaxf(qt-q4+Rq4, EPV)), 60000.f);
                *(uint4*)&rsd[y * WW + col] = pack8(rL, rH);
            }
        }
    };
    #pragma unroll
    for (int t = 0; t < 31; ++t) step(t);
}

// ---------------- main: product boxes, full-width rows, 4 j per wave ------
// One wave per (z, 8-row seg). 15 steps. 1536 waves, XCD-chunked. (R19 form.)
// Vp[j] += p(row c) - p(row c-8); subtract rows via 2-slack reload (exact
// fp16 telescoping). Emit window centered (7 bp / 8 cols / j).
__global__ void __launch_bounds__(64)
__attribute__((amdgpu_waves_per_eu(2, 2)))
ncc_f8(const __half* __restrict__ ac, const __half* __restrict__ rs,
       float* __restrict__ wsum)
{
    const int l   = threadIdx.x;
    const int n   = blockIdx.x;            // 0..1535
    const int xcd = n & 7;
    const int p   = n >> 3;                // 0..191
    const int zq  = p >> 6;                // 0..2
    const int seg = p & 63;                // 0..63
    const int z   = 3 * xcd + zq;          // b*6 + i
    const int b   = z / 6;
    const int y0  = 8 * seg;

    const __half* acp = ac + z * HW;
    const __half* sip = rs + z * HW;
    const __half* bcp[4]; const __half* sjp[4];
    #pragma unroll
    for (int j = 0; j < 4; ++j) {
        bcp[j] = ac + (24 + b * 4 + j) * HW;
        sjp[j] = rs + (24 + b * 4 + j) * HW;
    }

    const int   col = 8 * l;
    const int   aL1 = ((l - 1) & 63) << 2;
    const int   aR1 = ((l + 1) & 63) << 2;
    const float lmE = (l > 0)  ? 1.f : 0.f;
    const float rmE = (l < 63) ? 1.f : 0.f;

    uint4 fa[2], fb[4][2];                 // add rows (2-slack)
    uint4 oA[2], oB[4][2];                 // subtract rows (2-slack)
    {
        const int r0 = rcl(y0 - 3), r1 = rcl(y0 - 2);
        fa[0] = *(const uint4*)&acp[r0 * WW + col];
        fa[1] = *(const uint4*)&acp[r1 * WW + col];
        #pragma unroll
        for (int j = 0; j < 4; ++j) {
            fb[j][0] = *(const uint4*)&bcp[j][r0 * WW + col];
            fb[j][1] = *(const uint4*)&bcp[j][r1 * WW + col];
            oB[j][0] = make_uint4(0,0,0,0); oB[j][1] = make_uint4(0,0,0,0);
        }
        oA[0] = make_uint4(0,0,0,0); oA[1] = make_uint4(0,0,0,0);
    }

    float4 VpL[4], VpH[4];
    uint4 psiB[2], psjB[2][4];
    float4 xsL = make_float4(0,0,0,0), xsH = make_float4(0,0,0,0);
    #pragma unroll
    for (int j = 0; j < 4; ++j) {
        VpL[j] = make_float4(0,0,0,0); VpH[j] = make_float4(0,0,0,0);
        psjB[0][j] = make_uint4(0,0,0,0); psjB[1][j] = make_uint4(0,0,0,0);
    }
    psiB[0] = make_uint4(0,0,0,0); psiB[1] = make_uint4(0,0,0,0);

    auto step = [&](const int t) {
        const int   c  = y0 - 3 + t;                 // row being ADDED
        const float rm = (c >= 0 && c < HH) ? 1.f : 0.f;
        uint4 ar = fa[t & 1];
        uint4 br0 = fb[0][t & 1], br1 = fb[1][t & 1];
        uint4 br2 = fb[2][t & 1], br3 = fb[3][t & 1];
        uint4 arO = oA[t & 1];                       // row c-8 (valid t>=8)
        uint4 bo0 = oB[0][t & 1], bo1 = oB[1][t & 1];
        uint4 bo2 = oB[2][t & 1], bo3 = oB[3][t & 1];
        if (t <= 12) {                               // add-row prefetch
            const int rn = rcl(c + 2);
            fa[t & 1] = *(const uint4*)&acp[rn * WW + col];
            #pragma unroll
            for (int j = 0; j < 4; ++j)
                fb[j][t & 1] = *(const uint4*)&bcp[j][rn * WW + col];
        }
        if (t >= 6 && t <= 12) {                     // subtract-row prefetch
            const int ro = rcl(c - 6);               // used at t+2 (row c-6)
            oA[t & 1] = *(const uint4*)&acp[ro * WW + col];
            #pragma unroll
            for (int j = 0; j < 4; ++j)
                oB[j][t & 1] = *(const uint4*)&bcp[j][ro * WW + col];
        }
        {   // add products of row c
            float4 avL, avH; unpack8(ar, avL, avH);
            avL.x *= rm; avL.y *= rm; avL.z *= rm; avL.w *= rm;
            avH.x *= rm; avH.y *= rm; avH.z *= rm; avH.w *= rm;
            float4 bL, bH;
            unpack8(br0, bL, bH);
            VpL[0].x += avL.x*bL.x; VpL[0].y += avL.y*bL.y; VpL[0].z += avL.z*bL.z; VpL[0].w += avL.w*bL.w;
            VpH[0].x += avH.x*bH.x; VpH[0].y += avH.y*bH.y; VpH[0].z += avH.z*bH.z; VpH[0].w += avH.w*bH.w;
            unpack8(br1, bL, bH);
            VpL[1].x += avL.x*bL.x; VpL[1].y += avL.y*bL.y; VpL[1].z += avL.z*bL.z; VpL[1].w += avL.w*bL.w;
            VpH[1].x += avH.x*bH.x; VpH[1].y += avH.y*bH.y; VpH[1].z += avH.z*bH.z; VpH[1].w += avH.w*bH.w;
            unpack8(br2, bL, bH);
            VpL[2].x += avL.x*bL.x; VpL[2].y += avL.y*bL.y; VpL[2].z += avL.z*bL.z; VpL[2].w += avL.w*bL.w;
            VpH[2].x += avH.x*bH.x; VpH[2].y += avH.y*bH.y; VpH[2].z += avH.z*bH.z; VpH[2].w += avH.w*bH.w;
            unpack8(br3, bL, bH);
            VpL[3].x += avL.x*bL.x; VpL[3].y += avL.y*bL.y; VpL[3].z += avL.z*bL.z; VpL[3].w += avL.w*bL.w;
            VpH[3].x += avH.x*bH.x; VpH[3].y += avH.y*bH.y; VpH[3].z += avH.z*bH.z; VpH[3].w += avH.w*bH.w;
        }
        if (t >= 8) {   // subtract products of row c-8
            const float rmO = ((c - 8) >= 0) ? 1.f : 0.f;
            float4 avL, avH; unpack8(arO, avL, avH);
            avL.x *= rmO; avL.y *= rmO; avL.z *= rmO; avL.w *= rmO;
            avH.x *= rmO; avH.y *= rmO; avH.z *= rmO; avH.w *= rmO;
            float4 bL, bH;
            unpack8(bo0, bL, bH);
            VpL[0].x -= avL.x*bL.x; VpL[0].y -= avL.y*bL.y; VpL[0].z -= avL.z*bL.z; VpL[0].w -= avL.w*bL.w;
            VpH[0].x -= avH.x*bH.x; VpH[0].y -= avH.y*bH.y; VpH[0].z -= avH.z*bH.z; VpH[0].w -= avH.w*bH.w;
            unpack8(bo1, bL, bH);
            VpL[1].x -= avL.x*bL.x; VpL[1].y -= avL.y*bL.y; VpL[1].z -= avL.z*bL.z; VpL[1].w -= avL.w*bL.w;
            VpH[1].x -= avH.x*bH.x; VpH[1].y -= avH.y*bH.y; VpH[1].z -= avH.z*bH.z; VpH[1].w -= avH.w*bH.w;
            unpack8(bo2, bL, bH);
            VpL[2].x -= avL.x*bL.x; VpL[2].y -= avL.y*bL.y; VpL[2].z -= avL.z*bL.z; VpL[2].w -= avL.w*bL.w;
            VpH[2].x -= avH.x*bH.x; VpH[2].y -= avH.y*bH.y; VpH[2].z -= avH.z*bH.z; VpH[2].w -= avH.w*bH.w;
            unpack8(bo3, bL, bH);
            VpL[3].x -= avL.x*bL.x; VpL[3].y -= avL.y*bL.y; VpL[3].z -= avL.z*bL.z; VpL[3].w -= avL.w*bL.w;
            VpH[3].x -= avH.x*bH.x; VpH[3].y -= avH.y*bH.y; VpH[3].z -= avH.z*bH.z; VpH[3].w -= avH.w*bH.w;
        }
        if (t >= 7 && t <= 14) {   // emit row y = y0+t-7 (all cols valid)
            float4 pL, pH; unpack8(psiB[t & 1], pL, pH);
            float4 mmL = make_float4(-1,-1,-1,-1), mmH = make_float4(-1,-1,-1,-1);
            #pragma unroll
            for (int j = 0; j < 4; ++j) {
                float q1 = VpL[j].x, q2 = q1+VpL[j].y, q3 = q2+VpL[j].z, q4 = q3+VpL[j].w;
                float q5 = q4+VpH[j].x, q6 = q5+VpH[j].y, q7 = q6+VpH[j].z, q8 = q7+VpH[j].w;
                float s1 = VpH[j].w, s2 = VpH[j].z+s1, s3 = VpH[j].y+s2;
                float L1 = bpl(aL1, s1)*lmE, L2 = bpl(aL1, s2)*lmE, L3 = bpl(aL1, s3)*lmE;
                float R1 = bpl(aR1, q1)*rmE, R2 = bpl(aR1, q2)*rmE;
                float R3 = bpl(aR1, q3)*rmE, R4 = bpl(aR1, q4)*rmE;
                float4 sL, sH; unpack8(psjB[t & 1][j], sL, sH);
                mmL.x = fmaxf(mmL.x, (L3+q5)    * (pL.x*sL.x));
                mmL.y = fmaxf(mmL.y, (L2+q6)    * (pL.y*sL.y));
                mmL.z = fmaxf(mmL.z, (L1+q7)    * (pL.z*sL.z));
                mmL.w = fmaxf(mmL.w, q8         * (pL.w*sL.w));
                mmH.x = fmaxf(mmH.x, (q8-q1+R1) * (pH.x*sH.x));
                mmH.y = fmaxf(mmH.y, (q8-q2+R2) * (pH.y*sH.y));
                mmH.z = fmaxf(mmH.z, (q8-q3+R3) * (pH.z*sH.z));
                mmH.w = fmaxf(mmH.w, (q8-q4+R4) * (pH.w*sH.w));
            }
            xsL.x += 1.f - fminf(mmL.x, 1.f);
            xsL.y += 1.f - fminf(mmL.y, 1.f);
            xsL.z += 1.f - fminf(mmL.z, 1.f);
            xsL.w += 1.f - fminf(mmL.w, 1.f);
            xsH.x += 1.f - fminf(mmH.x, 1.f);
            xsH.y += 1.f - fminf(mmH.y, 1.f);
            xsH.z += 1.f - fminf(mmH.z, 1.f);
            xsH.w += 1.f - fminf(mmH.w, 1.f);
        }
        if (t >= 5 && t <= 12) {   // denom prefetch, 2-step slack
            const int yn = min(y0 + t - 5, HH - 1);
            psiB[t & 1] = *(const uint4*)&sip[yn * WW + col];
            #pragma unroll
            for (int j = 0; j < 4; ++j)
                psjB[t & 1][j] = *(const uint4*)&sjp[j][yn * WW + col];
        }
    };
    #pragma unroll
    for (int t = 0; t < 15; ++t) step(t);

    float xt = xsL.x + xsL.y + xsL.z + xsL.w + xsH.x + xsH.y + xsH.z + xsH.w;
    #pragma unroll
    for (int off = 32; off > 0; off >>= 1) xt += __shfl_down(xt, off);
    if (l == 0) atomicAdd(&wsum[z * 64], xt);
}

// ---------------- finalize: 24 partials -> 25 outputs ---------------------
__global__ void fin_f4(const float* __restrict__ wsum, float* __restrict__ out)
{
    const int l = threadIdx.x;
    float v = (l < 24) ? wsum[l * 64] : 0.f;
    if (l < 24) out[1 + l] = v * (1.f / (float)HW);
    #pragma unroll
    for (int off = 32; off > 0; off >>= 1) v += __shfl_down(v, off);
    if (l == 0) out[0] = v * (1.f / (24.f * (float)HW));
}

extern "C" void kernel_launch(void* const* d_in, const int* in_sizes, int n_in,
                              void* d_out, int out_size, void* d_ws, size_t ws_size,
                              hipStream_t stream) {
    const float* outs = (const float*)d_in[0];   // (4,6,512,512)
    const float* labs = (const float*)d_in[1];   // (4,4,512,512)
    float* out = (float*)d_out;                  // 25 floats
    float* ws  = (float*)d_ws;

    __half* acw  = (__half*)ws;            // 40*HW halves (a:0..23, b:24..39)
    __half* rsw  = (__half*)ws + 40 * HW;  // 40*HW halves (fp16 1/sqrt(var))
    float*  wsum = ws + 40 * HW;           // floats: after the two half arrays

    // prep: 32 segs(16 rows) x 40 images = 1280 waves (also zeroes wsum)
    prep_f8<<<dim3(32, 40), 64, 0, stream>>>(outs, labs, acw, rsw, wsum);
    // main: 1536 blocks (24 z x 64 segs of 8 rows), XCD-chunked decode
    ncc_f8<<<dim3(1536, 1, 1), 64, 0, stream>>>(acw, rsw, wsum);
    // finalize: one wave
    fin_f4<<<dim3(1, 1, 1), 64, 0, stream>>>(wsum, out);
}